// Round 4
// baseline (61432.855 us; speedup 1.0000x reference)
//
#include <hip/hip_runtime.h>

// Problem dims
#define Lz   128
#define Hd   1024
#define Od   64
#define Sq   256
#define Bt   512
#define K1   2176   // h1(1024) | h2(1024) | z(128)
#define K2q  2048   // h1n(1024) | h2(1024)
#define G4H  4096
#define NBLK 256u   // 64 ng-groups x 4 k-quarters; 1 block/CU (LDS-bound)

typedef __attribute__((ext_vector_type(8))) short  short8;
typedef __attribute__((ext_vector_type(4))) float  floatx4;

__device__ __forceinline__ short f2bf(float x) {
  unsigned u = __float_as_uint(x);
  unsigned r = (u + 0x7fffu + ((u >> 16) & 1u)) >> 16;
  return (short)r;
}
__device__ __forceinline__ float bf2f(short s) {
  return __uint_as_float(((unsigned)(unsigned short)s) << 16);
}
__device__ __forceinline__ float sigf(float x)   { return 1.0f / (1.0f + __expf(-x)); }
__device__ __forceinline__ float tanhf_(float x) { return 1.0f - 2.0f / (__expf(2.0f * x) + 1.0f); }

__device__ __forceinline__ void gl_lds(const short* g, void* l) {
  __builtin_amdgcn_global_load_lds(
      (__attribute__((address_space(1))) const void*)g,
      (__attribute__((address_space(3))) void*)l, 16, 0, 0);
}

// ---- grid barrier: 1 release-add per block, relaxed polls, 1 acquire fence ----
__device__ __forceinline__ void gbar(unsigned* cnt, unsigned* gen) {
  __syncthreads();
  if (threadIdx.x == 0) {
    unsigned g = __hip_atomic_load(gen, __ATOMIC_RELAXED, __HIP_MEMORY_SCOPE_AGENT);
    unsigned a = __hip_atomic_fetch_add(cnt, 1u, __ATOMIC_RELEASE, __HIP_MEMORY_SCOPE_AGENT);
    if (a == NBLK - 1u) {
      __builtin_amdgcn_fence(__ATOMIC_ACQUIRE, "agent");
      __hip_atomic_store(cnt, 0u, __ATOMIC_RELAXED, __HIP_MEMORY_SCOPE_AGENT);
      __hip_atomic_store(gen, g + 1u, __ATOMIC_RELEASE, __HIP_MEMORY_SCOPE_AGENT);
    } else {
      for (;;) {
        bool done = false;
        for (int i = 0; i < 16; ++i) {
          if (__hip_atomic_load(gen, __ATOMIC_RELAXED, __HIP_MEMORY_SCOPE_AGENT) != g) { done = true; break; }
          __builtin_amdgcn_s_sleep(2);
        }
        if (done) break;
        if (__hip_atomic_load(gen, __ATOMIC_ACQUIRE, __HIP_MEMORY_SCOPE_AGENT) != g) break;
      }
      __builtin_amdgcn_fence(__ATOMIC_ACQUIRE, "agent");
    }
  }
  __syncthreads();
}

// ---- weight row reorder: group bn (0..63) holds 64 rows: gate g (ifgo), j (0..15)
__device__ __forceinline__ int oldrow(int nr) {
  int bn = nr >> 6, rem = nr & 63, g = rem >> 4, jj = rem & 15;
  return g * Hd + bn * 16 + jj;
}

struct Params {
  const short *W1f, *W2f, *Woutb;
  const float *b0v, *b1v, *bpro, *bout;
  short *A1_0, *A1_1, *A2_0, *A2_1;
  float *c1, *c2, *out, *pscr;
  unsigned *bcnt, *bgen;
  int *flagsA, *flagsB;
};

// ================= prep kernels (row-major fold — proven in R3) =================
__global__ void k_conv_w1a(const float* __restrict__ Whh0, short* __restrict__ W1r) {
  int idx = blockIdx.x * 256 + threadIdx.x;        // 4096*1024
  int nr = idx >> 10, k = idx & 1023;
  W1r[nr * K1 + k] = f2bf(Whh0[oldrow(nr) * Hd + k]);
}
__global__ void k_conv_w1b(const float* __restrict__ Wih0, const float* __restrict__ Wout,
                           short* __restrict__ W1r) {
  int idx = blockIdx.x * 256 + threadIdx.x;        // 4096*1024  (W0out = Wih0p @ Wout)
  int nr = idx >> 10, c = idx & 1023;
  const float* wp = Wih0 + oldrow(nr) * (Lz + Od) + Lz;
  float acc = 0.f;
  #pragma unroll 8
  for (int q = 0; q < Od; ++q) acc += wp[q] * Wout[q * Hd + c];
  W1r[nr * K1 + Hd + c] = f2bf(acc);
}
__global__ void k_conv_w1c(const float* __restrict__ Wih0, short* __restrict__ W1r) {
  int idx = blockIdx.x * 256 + threadIdx.x;        // 4096*128
  int nr = idx >> 7, kz = idx & 127;
  W1r[nr * K1 + 2048 + kz] = f2bf(Wih0[oldrow(nr) * (Lz + Od) + kz]);
}
__global__ void k_conv_w2(const float* __restrict__ Wih1, const float* __restrict__ Whh1,
                          short* __restrict__ W2r) {
  int idx = blockIdx.x * 256 + threadIdx.x;        // 4096*2048
  int nr = idx >> 11, k = idx & 2047;
  int orow = oldrow(nr);
  float v = (k < Hd) ? Wih1[orow * Hd + k] : Whh1[orow * Hd + (k - Hd)];
  W2r[nr * K2q + k] = f2bf(v);
}
__global__ void k_conv_wout(const float* __restrict__ Wout, short* __restrict__ Woutb) {
  int idx = blockIdx.x * 256 + threadIdx.x;        // 64*1024
  Woutb[idx] = f2bf(Wout[idx]);
}
// fragment-major reorder: chunk c -> (ng, kh, s, g, q, n); 16B chunk = 8 consecutive k
__global__ void k_frag1(const short* __restrict__ W1r, short* __restrict__ W1f) {
  int c = blockIdx.x * 256 + threadIdx.x;          // 4096*2176/8 = 1,114,112 chunks
  int n = c & 15, q = (c >> 4) & 3, g = (c >> 6) & 3;
  int rest = c >> 8;                                // (ng*4+kh)*17 + s
  int s = rest % 17, t2 = rest / 17;
  int kh = t2 & 3, ng = t2 >> 2;
  const short8 v = *(const short8*)(W1r + (size_t)(ng * 64 + g * 16 + n) * K1 + kh * 544 + s * 32 + q * 8);
  *(short8*)(W1f + (size_t)c * 8) = v;
}
__global__ void k_frag2(const short* __restrict__ W2r, short* __restrict__ W2f) {
  int c = blockIdx.x * 256 + threadIdx.x;          // 4096*2048/8 = 1,048,576 chunks
  int n = c & 15, q = (c >> 4) & 3, g = (c >> 6) & 3;
  int rest = c >> 8;                                // (ng*4+kh)*16 + s
  int s = rest & 15, t2 = rest >> 4;
  int kh = t2 & 3, ng = t2 >> 2;
  const short8 v = *(const short8*)(W2r + (size_t)(ng * 64 + g * 16 + n) * K2q + kh * 512 + s * 32 + q * 8);
  *(short8*)(W2f + (size_t)c * 8) = v;
}
__global__ void k_vec(const float* __restrict__ bih0, const float* __restrict__ bhh0,
                      const float* __restrict__ bih1, const float* __restrict__ bhh1,
                      const float* __restrict__ Wih0, const float* __restrict__ bout,
                      float* __restrict__ b0v, float* __restrict__ b1v, float* __restrict__ bpro,
                      int* __restrict__ barzero) {
  int n = blockIdx.x * 256 + threadIdx.x;          // 4096 (original gate order)
  if (n < 1024) barzero[n] = 0;                    // zero barrier+flag state every launch
  b0v[n] = bih0[n] + bhh0[n];
  b1v[n] = bih1[n] + bhh1[n];
  const float* wp = Wih0 + n * (Lz + Od) + Lz;
  float acc = 0.f;
  #pragma unroll 8
  for (int q = 0; q < Od; ++q) acc += wp[q] * bout[q];
  bpro[n] = acc;
}
__global__ void k_init(const float* __restrict__ z, const float* __restrict__ Wh,
                       const float* __restrict__ bh, const float* __restrict__ Wc,
                       const float* __restrict__ bc,
                       short* __restrict__ A1_0, short* __restrict__ A2_0,
                       float* __restrict__ c1, float* __restrict__ c2) {
  int idx = blockIdx.x * 256 + threadIdx.x;        // 512*1024
  int m = idx >> 10, n = idx & 1023;
  const float* zr = z + m * Lz;
  const float* whr = Wh + n * Lz;
  const float* wcr = Wc + n * Lz;
  float hh = bh[n], cc = bc[n];
  #pragma unroll 8
  for (int k = 0; k < Lz; ++k) { float zv = zr[k]; hh += zv * whr[k]; cc += zv * wcr[k]; }
  c1[idx] = cc;
  c2[idx] = cc;
  short hb = f2bf(hh);
  A1_0[m * K1 + n] = hb;            // h1(-1) = h0
  A1_0[m * K1 + Hd + n] = 0;        // h2 slot at t=0: no feedback
  A2_0[m * K2q + Hd + n] = hb;      // h2(-1) = h0 for layer-1 at t=0
}
__global__ void k_initz(const float* __restrict__ z, short* __restrict__ A1_0,
                        short* __restrict__ A1_1) {
  int idx = blockIdx.x * 256 + threadIdx.x;        // 512*128
  int m = idx >> 7, k = idx & 127;
  short v = f2bf(z[idx]);
  A1_0[m * K1 + 2048 + k] = v;
  A1_1[m * K1 + 2048 + k] = v;
}

// ================= main persistent kernel =================
#define MFMA16(a, b, c) __builtin_amdgcn_mfma_f32_16x16x32_bf16(a, b, c, 0, 0, 0)

// GEMM over one K-quarter. Wave w owns m-rows [w*128, w*128+128) (8 m-tiles).
// B (weights) from LDS fragment layout; A (activations) streamed from global.
__device__ __forceinline__ void gemm_q(const short* __restrict__ A, int astride, int kq0,
                                       int nsteps, const short* __restrict__ Wlds,
                                       int tid, floatx4 acc[8][4]) {
  const int lane = tid & 63, w = tid >> 6, l15 = lane & 15, q = lane >> 4;
  const short* ap = A + (size_t)(w * 128 + l15) * astride + kq0 + q * 8;
  short8 cur[8], nxt[8];
  #pragma unroll
  for (int mt = 0; mt < 8; ++mt) cur[mt] = *(const short8*)(ap + mt * 16 * astride);
  for (int s = 0; s < nsteps; ++s) {
    if (s + 1 < nsteps) {
      #pragma unroll
      for (int mt = 0; mt < 8; ++mt)
        nxt[mt] = *(const short8*)(ap + mt * 16 * astride + (s + 1) * 32);
    }
    #pragma unroll
    for (int g = 0; g < 4; ++g) {
      short8 b = *(const short8*)(Wlds + ((s * 16 + g * 4 + q) * 16 + l15) * 8);
      #pragma unroll
      for (int mt = 0; mt < 8; ++mt) acc[mt][g] = MFMA16(cur[mt], b, acc[mt][g]);
    }
    #pragma unroll
    for (int mt = 0; mt < 8; ++mt) cur[mt] = nxt[mt];
  }
}

__device__ __forceinline__ void store_partial(float* __restrict__ ps, int tid, floatx4 acc[8][4]) {
  floatx4* dst = (floatx4*)ps;
  #pragma unroll
  for (int mt = 0; mt < 8; ++mt)
    #pragma unroll
    for (int g = 0; g < 4; ++g)
      dst[(mt * 4 + g) * 256 + tid] = acc[mt][g];
}
__device__ __forceinline__ void load_add_partial(const float* __restrict__ ps, int tid, floatx4 acc[8][4]) {
  const floatx4* srcp = (const floatx4*)ps;
  #pragma unroll
  for (int mt = 0; mt < 8; ++mt)
    #pragma unroll
    for (int g = 0; g < 4; ++g) {
      floatx4 v = srcp[(mt * 4 + g) * 256 + tid];
      acc[mt][g][0] += v[0]; acc[mt][g][1] += v[1];
      acc[mt][g][2] += v[2]; acc[mt][g][3] += v[3];
    }
}

// Fused LSTM cell epilogue (kh==0 blocks), gate-per-n-tile layout from R3 (proven).
__device__ __forceinline__ void epilogue(floatx4 acc[8][4], const float* bz, float cr[8][4],
    short* __restrict__ hd0, int hs0, int ho0,
    short* __restrict__ hd1, int hs1, int ho1, int colh, int tid) {
  const int lane = tid & 63, w = tid >> 6, q = lane >> 4;
  #pragma unroll
  for (int mt = 0; mt < 8; ++mt) {
    #pragma unroll
    for (int r = 0; r < 4; ++r) {
      const int mg = w * 128 + mt * 16 + q * 4 + r;
      float iv = acc[mt][0][r] + bz[0];
      float fv = acc[mt][1][r] + bz[1];
      float gv = acc[mt][2][r] + bz[2];
      float ov = acc[mt][3][r] + bz[3];
      float cn = sigf(fv) * cr[mt][r] + sigf(iv) * tanhf_(gv);
      cr[mt][r] = cn;
      short hb = f2bf(sigf(ov) * tanhf_(cn));
      hd0[mg * hs0 + ho0 + colh] = hb;
      hd1[mg * hs1 + ho1 + colh] = hb;
    }
  }
}

// VALU out-projection duty (kh==3 blocks): out[tt] = h2(tt) @ Wout.T + bout
__device__ __forceinline__ void out_duty(const short* __restrict__ A1p,
    const short* __restrict__ Wos, const float* __restrict__ bout,
    float* __restrict__ out, int tt, int ng, int tid) {
  const int cg = ng & 7, bg = ng >> 3;
  const int o = tid & 7, mi = tid >> 3;
  const int m = bg * 64 + mi * 2;
  float a0 = 0.f, a1 = 0.f;
  const short* r0 = A1p + (size_t)m * K1 + 1024;
  const short* r1 = r0 + K1;
  const short* wr = Wos + o * 1040;
  for (int kc = 0; kc < 128; ++kc) {
    short8 x0 = *(const short8*)(r0 + kc * 8);
    short8 x1 = *(const short8*)(r1 + kc * 8);
    short8 wv = *(const short8*)(wr + kc * 8);
    #pragma unroll
    for (int j = 0; j < 8; ++j) {
      float wf = bf2f(wv[j]);
      a0 += bf2f(x0[j]) * wf;
      a1 += bf2f(x1[j]) * wf;
    }
  }
  float bo = bout[cg * 8 + o];
  out[(size_t)m * (Sq * Od) + tt * Od + cg * 8 + o] = a0 + bo;
  out[(size_t)(m + 1) * (Sq * Od) + tt * Od + cg * 8 + o] = a1 + bo;
}

__global__ __launch_bounds__(256, 1) void lstm_main(Params p) {
  extern __shared__ __align__(16) short smem[];
  short* W1s = smem;                 // 34816 shorts (68 KB)
  short* W2s = smem + 34816;         // 32768 shorts (64 KB)
  short* Wos = smem + 67584;         // 8*1040 shorts (16.25 KB)
  const int tid = threadIdx.x;
  const int blk = blockIdx.x;
  const int xcd = blk & 7, slot = blk >> 3;
  const int ng = xcd * 8 + (slot & 7);   // 0..63: 16 hidden cols x 4 gates
  const int kh = slot >> 3;              // 0..3: K-quarter
  const int lane = tid & 63, w = tid >> 6, l15 = lane & 15, q = lane >> 4;
  const int colh = ng * 16 + l15;

  // ---- one-time: load resident weight quarters into LDS ----
  {
    const short* s1 = p.W1f + (size_t)(ng * 4 + kh) * 34816;
    for (int i = 0; i < 17; ++i) gl_lds(s1 + (i * 256 + tid) * 8, W1s + (i * 256 + tid) * 8);
    const short* s2 = p.W2f + (size_t)(ng * 4 + kh) * 32768;
    for (int i = 0; i < 16; ++i) gl_lds(s2 + (i * 256 + tid) * 8, W2s + (i * 256 + tid) * 8);
    if (kh == 3) {
      const int cg = ng & 7;
      #pragma unroll
      for (int i = 0; i < 4; ++i) {
        int c = i * 256 + tid, oo = c >> 7, kc = c & 127;
        *(short8*)(Wos + oo * 1040 + kc * 8) = *(const short8*)(p.Woutb + (cg * 8 + oo) * 1024 + kc * 8);
      }
    }
    asm volatile("s_waitcnt vmcnt(0)" ::: "memory");
    __syncthreads();
  }

  // ---- per-sequence registers (kh==0 blocks own epilogue + cell state) ----
  float bA[4], bAP[4], bB[4], c1r[8][4], c2r[8][4];
  if (kh == 0) {
    #pragma unroll
    for (int g = 0; g < 4; ++g) {
      bA[g]  = p.b0v[g * Hd + colh];
      bAP[g] = bA[g] + p.bpro[g * Hd + colh];
      bB[g]  = p.b1v[g * Hd + colh];
    }
    #pragma unroll
    for (int mt = 0; mt < 8; ++mt)
      #pragma unroll
      for (int r = 0; r < 4; ++r) {
        const int mg = w * 128 + mt * 16 + q * 4 + r;
        c1r[mt][r] = p.c1[mg * Hd + colh];
        c2r[mt][r] = p.c2[mg * Hd + colh];
      }
  }

  float* mypsc = p.pscr + (size_t)(ng * 3 + (kh - 1)) * 32768;  // valid for kh>0

  for (int t = 0; t < Sq; ++t) {
    const int par = t & 1;
    const short* A1p = par ? p.A1_1 : p.A1_0;
    short* A1n = par ? p.A1_0 : p.A1_1;
    short* A2p = par ? p.A2_1 : p.A2_0;
    short* A2n = par ? p.A2_0 : p.A2_1;

    // ======== phase A: layer-0 gates (h1, h2-fold, z) ========
    {
      floatx4 acc[8][4] = {};
      gemm_q(A1p, K1, kh * 544, 17, W1s, tid, acc);
      if (kh > 0) {
        store_partial(mypsc, tid, acc);
        __syncthreads();                       // drains vmcnt before barrier
        if (tid == 0) {
          __builtin_amdgcn_fence(__ATOMIC_RELEASE, "agent");
          __hip_atomic_store(&p.flagsA[ng * 4 + kh], t + 1, __ATOMIC_RELAXED, __HIP_MEMORY_SCOPE_AGENT);
        }
        if (kh == 3 && t > 0) out_duty(A1p, Wos, p.bout, p.out, t - 1, ng, tid);
      } else {
        if (tid == 0) {
          for (int j = 1; j < 4; ++j)
            while (__hip_atomic_load(&p.flagsA[ng * 4 + j], __ATOMIC_RELAXED, __HIP_MEMORY_SCOPE_AGENT) != t + 1)
              __builtin_amdgcn_s_sleep(1);
          __builtin_amdgcn_fence(__ATOMIC_ACQUIRE, "agent");
        }
        __syncthreads();
        #pragma unroll
        for (int j = 1; j < 4; ++j)
          load_add_partial(p.pscr + (size_t)(ng * 3 + (j - 1)) * 32768, tid, acc);
        epilogue(acc, (t > 0) ? bAP : bA, c1r, A1n, K1, 0, A2p, K2q, 0, colh, tid);
      }
    }
    gbar(p.bcnt, p.bgen);

    // ======== phase B: layer-1 gates ========
    {
      floatx4 acc[8][4] = {};
      gemm_q(A2p, K2q, kh * 512, 16, W2s, tid, acc);
      if (kh > 0) {
        store_partial(mypsc, tid, acc);
        __syncthreads();
        if (tid == 0) {
          __builtin_amdgcn_fence(__ATOMIC_RELEASE, "agent");
          __hip_atomic_store(&p.flagsB[ng * 4 + kh], t + 1, __ATOMIC_RELAXED, __HIP_MEMORY_SCOPE_AGENT);
        }
      } else {
        if (tid == 0) {
          for (int j = 1; j < 4; ++j)
            while (__hip_atomic_load(&p.flagsB[ng * 4 + j], __ATOMIC_RELAXED, __HIP_MEMORY_SCOPE_AGENT) != t + 1)
              __builtin_amdgcn_s_sleep(1);
          __builtin_amdgcn_fence(__ATOMIC_ACQUIRE, "agent");
        }
        __syncthreads();
        #pragma unroll
        for (int j = 1; j < 4; ++j)
          load_add_partial(p.pscr + (size_t)(ng * 3 + (j - 1)) * 32768, tid, acc);
        epilogue(acc, bB, c2r, A2n, K2q, Hd, A1n, K1, Hd, colh, tid);
      }
    }
    gbar(p.bcnt, p.bgen);
  }

  // final out: t = Sq-1; h2(255) lives in A1 buffer of parity Sq&1==0 -> A1_0
  if (kh == 3) out_duty(p.A1_0, Wos, p.bout, p.out, Sq - 1, ng, tid);
}

// ================= host =================
extern "C" void kernel_launch(void* const* d_in, const int* in_sizes, int n_in,
                              void* d_out, int out_size, void* d_ws, size_t ws_size,
                              hipStream_t stream) {
  const float* z    = (const float*)d_in[0];
  const float* Wh   = (const float*)d_in[1];
  const float* bh   = (const float*)d_in[2];
  const float* Wc   = (const float*)d_in[3];
  const float* bc   = (const float*)d_in[4];
  const float* Wih0 = (const float*)d_in[5];
  const float* Whh0 = (const float*)d_in[6];
  const float* bih0 = (const float*)d_in[7];
  const float* bhh0 = (const float*)d_in[8];
  const float* Wih1 = (const float*)d_in[9];
  const float* Whh1 = (const float*)d_in[10];
  const float* bih1 = (const float*)d_in[11];
  const float* bhh1 = (const float*)d_in[12];
  const float* Wout = (const float*)d_in[13];
  const float* bout = (const float*)d_in[14];
  float* out = (float*)d_out;

  char* ws = (char*)d_ws;
  size_t off = 0;
  auto carve = [&](size_t bytes) { char* p = ws + off; off = (off + bytes + 255) & ~size_t(255); return p; };
  short* W1r   = (short*)carve((size_t)G4H * K1 * 2);
  short* W2r   = (short*)carve((size_t)G4H * K2q * 2);
  short* W1f   = (short*)carve((size_t)G4H * K1 * 2);
  short* W2f   = (short*)carve((size_t)G4H * K2q * 2);
  short* Woutb = (short*)carve((size_t)Od * Hd * 2);
  float* b0v   = (float*)carve(G4H * 4);
  float* b1v   = (float*)carve(G4H * 4);
  float* bpro  = (float*)carve(G4H * 4);
  short* A1_0  = (short*)carve((size_t)Bt * K1 * 2);
  short* A1_1  = (short*)carve((size_t)Bt * K1 * 2);
  short* A2_0  = (short*)carve((size_t)Bt * K2q * 2);
  short* A2_1  = (short*)carve((size_t)Bt * K2q * 2);
  float* c1    = (float*)carve((size_t)Bt * Hd * 4);
  float* c2    = (float*)carve((size_t)Bt * Hd * 4);
  float* pscr  = (float*)carve((size_t)64 * 3 * 32768 * 4);
  int*   barr  = (int*)carve(4096);   // [0]=cnt [1]=gen, flagsA @ +64, flagsB @ +384

  k_conv_w1a<<<16384, 256, 0, stream>>>(Whh0, W1r);
  k_conv_w1b<<<16384, 256, 0, stream>>>(Wih0, Wout, W1r);
  k_conv_w1c<<<2048, 256, 0, stream>>>(Wih0, W1r);
  k_conv_w2 <<<32768, 256, 0, stream>>>(Wih1, Whh1, W2r);
  k_conv_wout<<<256, 256, 0, stream>>>(Wout, Woutb);
  k_frag1<<<4352, 256, 0, stream>>>(W1r, W1f);
  k_frag2<<<4096, 256, 0, stream>>>(W2r, W2f);
  k_vec<<<16, 256, 0, stream>>>(bih0, bhh0, bih1, bhh1, Wih0, bout, b0v, b1v, bpro, barr);
  k_init<<<2048, 256, 0, stream>>>(z, Wh, bh, Wc, bc, A1_0, A2_0, c1, c2);
  k_initz<<<256, 256, 0, stream>>>(z, A1_0, A1_1);

  Params pr{W1f, W2f, Woutb, b0v, b1v, bpro, bout,
            A1_0, A1_1, A2_0, A2_1, c1, c2, out, pscr,
            (unsigned*)barr, (unsigned*)(barr + 1), barr + 64, barr + 384};

  static bool attr_set = false;
  if (!attr_set) {
    (void)hipFuncSetAttribute((const void*)lstm_main,
                              hipFuncAttributeMaxDynamicSharedMemorySize, 151808);
    attr_set = true;
  }
  lstm_main<<<dim3(NBLK), dim3(256), 151808, stream>>>(pr);
}

// Round 5
// 15963.045 us; speedup vs baseline: 3.8484x; 3.8484x over previous
//
#include <hip/hip_runtime.h>

// Problem dims
#define Lz   128
#define Hd   1024
#define Od   64
#define Sq   256
#define Bt   512
#define K1   2176   // h1(1024) | h2(1024) | z(128)
#define K2q  2048   // h1n(1024) | h2(1024)
#define G4H  4096
#define NBLK 272u   // 256 GEMM (8 mb x 32 bn2, 64x128 tiles) + 16 out

typedef __attribute__((ext_vector_type(8))) short  short8;
typedef __attribute__((ext_vector_type(4))) float  floatx4;

__device__ __forceinline__ short f2bf(float x) {
  unsigned u = __float_as_uint(x);
  unsigned r = (u + 0x7fffu + ((u >> 16) & 1u)) >> 16;
  return (short)r;
}
__device__ __forceinline__ float sigf(float x)   { return 1.0f / (1.0f + __expf(-x)); }
__device__ __forceinline__ float tanhf_(float x) { return 1.0f - 2.0f / (__expf(2.0f * x) + 1.0f); }

// cached weight load (L2-resident; weights are static -> never stale)
__device__ __forceinline__ void gl_lds_w(const short* g, void* l) {
  __builtin_amdgcn_global_load_lds(
      (__attribute__((address_space(1))) const void*)g,
      (__attribute__((address_space(3))) void*)l, 16, 0, 0);
}
// coherent activation load: sc0|nt|sc1 = 1|2|16 -> force L2 miss (never stale),
// no L2 allocation (never evicts weights), reads MALL (sees write-through stores)
__device__ __forceinline__ void gl_lds_a(const short* g, void* l) {
  __builtin_amdgcn_global_load_lds(
      (__attribute__((address_space(1))) const void*)g,
      (__attribute__((address_space(3))) void*)l, 16, 0, 19);
}
// write-through coherent h-state store (visible at MALL to all XCDs)
__device__ __forceinline__ void st_wt(short* p, short v) {
  asm volatile("global_store_short %0, %1, off sc0 sc1"
               :: "v"(p), "v"((unsigned)(unsigned short)v) : "memory");
}

#define S_BARRIER() asm volatile("s_barrier" ::: "memory")
#define WAITVM(n)   asm volatile("s_waitcnt vmcnt(" #n ")" ::: "memory")

// ---- fence-free grid barrier: relaxed agent atomics only (visibility proven R4).
// No acquire fence -> L2 is never invalidated -> weights stay resident.
__device__ __forceinline__ void gbar(unsigned* cnt, unsigned* gen) {
  __syncthreads();   // also drains this block's vmcnt (write-through stores done)
  if (threadIdx.x == 0) {
    unsigned g = __hip_atomic_load(gen, __ATOMIC_RELAXED, __HIP_MEMORY_SCOPE_AGENT);
    unsigned a = __hip_atomic_fetch_add(cnt, 1u, __ATOMIC_RELAXED, __HIP_MEMORY_SCOPE_AGENT);
    if (a == NBLK - 1u) {
      __hip_atomic_store(cnt, 0u, __ATOMIC_RELAXED, __HIP_MEMORY_SCOPE_AGENT);
      __hip_atomic_store(gen, g + 1u, __ATOMIC_RELAXED, __HIP_MEMORY_SCOPE_AGENT);
    } else {
      while (__hip_atomic_load(gen, __ATOMIC_RELAXED, __HIP_MEMORY_SCOPE_AGENT) == g)
        __builtin_amdgcn_s_sleep(8);
    }
  }
  __syncthreads();
}

// ---- weight row reorder: group bn (0..63) holds 64 rows: gate g (ifgo), j (0..15)
__device__ __forceinline__ int oldrow(int nr) {
  int bn = nr >> 6, rem = nr & 63, g = rem >> 4, jj = rem & 15;
  return g * Hd + bn * 16 + jj;
}

struct Params {
  const short *W1r, *W2r, *Woutb;
  const float *b0v, *b1v, *bpro, *bout;
  short *A1_0, *A1_1, *A2_0, *A2_1;
  float *c1, *c2, *out;
  unsigned *bcnt, *bgen;
};

// ================= prep kernels (proven R3) =================
__global__ void k_conv_w1a(const float* __restrict__ Whh0, short* __restrict__ W1r) {
  int idx = blockIdx.x * 256 + threadIdx.x;
  int nr = idx >> 10, k = idx & 1023;
  W1r[nr * K1 + k] = f2bf(Whh0[oldrow(nr) * Hd + k]);
}
__global__ void k_conv_w1b(const float* __restrict__ Wih0, const float* __restrict__ Wout,
                           short* __restrict__ W1r) {
  int idx = blockIdx.x * 256 + threadIdx.x;
  int nr = idx >> 10, c = idx & 1023;
  const float* wp = Wih0 + oldrow(nr) * (Lz + Od) + Lz;
  float acc = 0.f;
  #pragma unroll 8
  for (int q = 0; q < Od; ++q) acc += wp[q] * Wout[q * Hd + c];
  W1r[nr * K1 + Hd + c] = f2bf(acc);
}
__global__ void k_conv_w1c(const float* __restrict__ Wih0, short* __restrict__ W1r) {
  int idx = blockIdx.x * 256 + threadIdx.x;
  int nr = idx >> 7, kz = idx & 127;
  W1r[nr * K1 + 2048 + kz] = f2bf(Wih0[oldrow(nr) * (Lz + Od) + kz]);
}
__global__ void k_conv_w2(const float* __restrict__ Wih1, const float* __restrict__ Whh1,
                          short* __restrict__ W2r) {
  int idx = blockIdx.x * 256 + threadIdx.x;
  int nr = idx >> 11, k = idx & 2047;
  int orow = oldrow(nr);
  float v = (k < Hd) ? Wih1[orow * Hd + k] : Whh1[orow * Hd + (k - Hd)];
  W2r[nr * K2q + k] = f2bf(v);
}
__global__ void k_conv_wout(const float* __restrict__ Wout, short* __restrict__ Woutb) {
  int idx = blockIdx.x * 256 + threadIdx.x;
  Woutb[idx] = f2bf(Wout[idx]);
}
__global__ void k_vec(const float* __restrict__ bih0, const float* __restrict__ bhh0,
                      const float* __restrict__ bih1, const float* __restrict__ bhh1,
                      const float* __restrict__ Wih0, const float* __restrict__ bout,
                      float* __restrict__ b0v, float* __restrict__ b1v, float* __restrict__ bpro,
                      unsigned* __restrict__ barzero) {
  int n = blockIdx.x * 256 + threadIdx.x;
  if (n < 64) barzero[n] = 0u;
  b0v[n] = bih0[n] + bhh0[n];
  b1v[n] = bih1[n] + bhh1[n];
  const float* wp = Wih0 + n * (Lz + Od) + Lz;
  float acc = 0.f;
  #pragma unroll 8
  for (int q = 0; q < Od; ++q) acc += wp[q] * bout[q];
  bpro[n] = acc;
}
__global__ void k_init(const float* __restrict__ z, const float* __restrict__ Wh,
                       const float* __restrict__ bh, const float* __restrict__ Wc,
                       const float* __restrict__ bc,
                       short* __restrict__ A1_0, short* __restrict__ A2_0,
                       float* __restrict__ c1, float* __restrict__ c2) {
  int idx = blockIdx.x * 256 + threadIdx.x;
  int m = idx >> 10, n = idx & 1023;
  const float* zr = z + m * Lz;
  const float* whr = Wh + n * Lz;
  const float* wcr = Wc + n * Lz;
  float hh = bh[n], cc = bc[n];
  #pragma unroll 8
  for (int k = 0; k < Lz; ++k) { float zv = zr[k]; hh += zv * whr[k]; cc += zv * wcr[k]; }
  c1[idx] = cc;
  c2[idx] = cc;
  short hb = f2bf(hh);
  A1_0[m * K1 + n] = hb;
  A1_0[m * K1 + Hd + n] = 0;
  A2_0[m * K2q + Hd + n] = hb;
}
__global__ void k_initz(const float* __restrict__ z, short* __restrict__ A1_0,
                        short* __restrict__ A1_1) {
  int idx = blockIdx.x * 256 + threadIdx.x;
  int m = idx >> 7, k = idx & 127;
  short v = f2bf(z[idx]);
  A1_0[m * K1 + 2048 + k] = v;
  A1_1[m * K1 + 2048 + k] = v;
}

// ================= main persistent kernel =================
#define MFMA16(a, b, c) __builtin_amdgcn_mfma_f32_16x16x32_bf16(a, b, c, 0, 0, 0)
#define BUFSH 12288   // shorts per LDS buffer: A 64x64 (4096) + W 128x64 (8192)

// 64x128 tile, 4 waves: w = mh*2+gh. mh: m-half (32 rows); gh: bn-group half (16 hcols x 4 gates).
// XOR-swizzled LDS (R3-proven formula): slot sl of row r holds global chunk sl^(r&7).
__device__ __forceinline__ void gemm_win(
    const short* __restrict__ Asrc, int astride, int nk,
    const short* __restrict__ Wsrc,
    const float* __restrict__ bz, float cr[2][4],
    short* __restrict__ hd0, int hs0, int ho0,
    short* __restrict__ hd1, int hs1, int ho1,
    int m0, int bn2, short* sm, int tid)
{
  const int lane = tid & 63, w = tid >> 6;
  const int l15 = lane & 15, q = lane >> 4;
  const int mh = w >> 1, gh = w & 1;
  floatx4 acc[2][4] = {};

  const short* Ab = Asrc + (size_t)m0 * astride;
  const short* Wb = Wsrc + (size_t)(bn2 * 128) * astride;   // W rows contiguous, same K stride

  auto stage = [&](int kk, int b) {
    const int kb = kk * 64;
    short* as = sm + b * BUFSH;
    short* ws = as + 4096;
    #pragma unroll
    for (int i = 0; i < 2; ++i) {
      int s = i * 256 + tid;
      int row = s >> 3, cg = (s & 7) ^ (row & 7);
      gl_lds_a(Ab + (size_t)row * astride + kb + cg * 8, as + s * 8);
    }
    #pragma unroll
    for (int i = 0; i < 4; ++i) {
      int s = i * 256 + tid;
      int row = s >> 3, cg = (s & 7) ^ (row & 7);
      gl_lds_w(Wb + (size_t)row * astride + kb + cg * 8, ws + s * 8);
    }
  };

  stage(0, 0);
  stage(1, 1);
  for (int kk = 0; kk < nk; ++kk) {
    S_BARRIER();                       // all waves done computing buf (kk+2)%3's old data
    if (kk + 2 < nk) { stage(kk + 2, (kk + 2) % 3); WAITVM(12); }
    else if (kk + 1 < nk) { WAITVM(6); }
    else { WAITVM(0); }
    S_BARRIER();                       // every wave's stage-kk portion landed
    const short* as = sm + (kk % 3) * BUFSH;
    const short* ws = as + 4096;
    #pragma unroll
    for (int ks = 0; ks < 2; ++ks) {
      const int cc = ks * 4 + q;
      short8 a[2];
      #pragma unroll
      for (int mt = 0; mt < 2; ++mt) {
        const int ra = mh * 32 + mt * 16 + l15;
        a[mt] = *(const short8*)(as + (ra * 8 + (cc ^ (ra & 7))) * 8);
      }
      #pragma unroll
      for (int g = 0; g < 4; ++g) {
        const int rw = gh * 64 + g * 16 + l15;
        short8 b = *(const short8*)(ws + (rw * 8 + (cc ^ (rw & 7))) * 8);
        acc[0][g] = MFMA16(a[0], b, acc[0][g]);
        acc[1][g] = MFMA16(a[1], b, acc[1][g]);
      }
    }
  }
  // fused LSTM cell epilogue; h written through to MALL (cross-XCD coherent)
  const int colh = bn2 * 32 + gh * 16 + l15;
  #pragma unroll
  for (int mt = 0; mt < 2; ++mt) {
    #pragma unroll
    for (int r = 0; r < 4; ++r) {
      const int mg = m0 + mh * 32 + mt * 16 + q * 4 + r;
      float iv = acc[mt][0][r] + bz[0];
      float fv = acc[mt][1][r] + bz[1];
      float gv = acc[mt][2][r] + bz[2];
      float ov = acc[mt][3][r] + bz[3];
      float cn = sigf(fv) * cr[mt][r] + sigf(iv) * tanhf_(gv);
      cr[mt][r] = cn;
      short hb = f2bf(sigf(ov) * tanhf_(cn));
      st_wt(hd0 + (size_t)mg * hs0 + ho0 + colh, hb);
      st_wt(hd1 + (size_t)mg * hs1 + ho1 + colh, hb);
    }
  }
}

// out-blocks: stage h2 slice (32 rows x 1024) coherently into LDS, MFMA vs cached Wout
__device__ __forceinline__ void out_win(const short* __restrict__ A1p,
    const short* __restrict__ Wo, const float* __restrict__ bout,
    float* __restrict__ out, int tt, int ob, short* sm, int tid)
{
  const int lane = tid & 63, w = tid >> 6;
  const int l15 = lane & 15, q = lane >> 4;
  const int ms = w & 1, nh = w >> 1;
  const int m0 = ob * 32;
  #pragma unroll
  for (int i = 0; i < 16; ++i) {
    int s = i * 256 + tid;
    int row = s >> 7, c = s & 127, cs = c ^ (row & 7);
    gl_lds_a(A1p + (size_t)(m0 + row) * K1 + 1024 + cs * 8, sm + s * 8);
  }
  WAITVM(0);
  __syncthreads();
  floatx4 acc[2] = {};
  const short* B0 = Wo + (nh * 32 + l15) * Hd;
  const int ra = ms * 16 + l15;
  for (int kk = 0; kk < Hd; kk += 32) {
    const int ch = (kk >> 3) + q;
    short8 a  = *(const short8*)(sm + (ra * 128 + (ch ^ (ra & 7))) * 8);
    short8 b0 = *(const short8*)(B0 + kk + q * 8);
    short8 b1 = *(const short8*)(B0 + 16 * Hd + kk + q * 8);
    acc[0] = MFMA16(a, b0, acc[0]);
    acc[1] = MFMA16(a, b1, acc[1]);
  }
  #pragma unroll
  for (int s = 0; s < 2; ++s)
    #pragma unroll
    for (int r = 0; r < 4; ++r) {
      int m = m0 + ms * 16 + q * 4 + r;
      int n = nh * 32 + s * 16 + l15;
      out[(size_t)m * (Sq * Od) + tt * Od + n] = acc[s][r] + bout[n];
    }
  __syncthreads();   // protect sm before next step's stage
}

__global__ __launch_bounds__(256, 2) void lstm_main(Params p) {
  extern __shared__ __align__(16) short smem[];   // 3 x 24 KB = 72 KB
  const int tid = threadIdx.x;
  const int blk = blockIdx.x;

  if (blk < 256) {
    // XCD-aware: 8 mb-sharers of one bn2 weight slice land on one XCD (heuristic)
    const int xcd = blk & 7, j = blk >> 3;
    const int bn2 = xcd * 4 + (j & 3);   // 0..31
    const int m0 = (j >> 2) * 64;        // mb 0..7
    const int lane = tid & 63, w = tid >> 6;
    const int l15 = lane & 15, q = lane >> 4;
    const int mh = w >> 1, gh = w & 1;
    const int colh = bn2 * 32 + gh * 16 + l15;

    float bA[4], bAP[4], bB[4], c1r[2][4], c2r[2][4];
    #pragma unroll
    for (int g = 0; g < 4; ++g) {
      bA[g]  = p.b0v[g * Hd + colh];
      bAP[g] = bA[g] + p.bpro[g * Hd + colh];
      bB[g]  = p.b1v[g * Hd + colh];
    }
    #pragma unroll
    for (int mt = 0; mt < 2; ++mt)
      #pragma unroll
      for (int r = 0; r < 4; ++r) {
        const int mg = m0 + mh * 32 + mt * 16 + q * 4 + r;
        c1r[mt][r] = p.c1[mg * Hd + colh];
        c2r[mt][r] = p.c2[mg * Hd + colh];
      }

    for (int t = 0; t < Sq; ++t) {
      const int par = t & 1;
      const short* A1p = par ? p.A1_1 : p.A1_0;
      short* A1n = par ? p.A1_0 : p.A1_1;
      short* A2p = par ? p.A2_1 : p.A2_0;
      short* A2n = par ? p.A2_0 : p.A2_1;
      gemm_win(A1p, K1, 34, p.W1r, (t > 0) ? bAP : bA, c1r,
               A1n, K1, 0, A2p, K2q, 0, m0, bn2, smem, tid);
      gbar(p.bcnt, p.bgen);
      gemm_win(A2p, K2q, 32, p.W2r, bB, c2r,
               A2n, K2q, Hd, A1n, K1, Hd, m0, bn2, smem, tid);
      gbar(p.bcnt, p.bgen);
    }
  } else {
    const int ob = blk - 256;   // 0..15
    for (int t = 0; t < Sq; ++t) {
      const short* A1p = (t & 1) ? p.A1_1 : p.A1_0;
      if (t > 0) out_win(A1p, p.Woutb, p.bout, p.out, t - 1, ob, smem, tid);
      gbar(p.bcnt, p.bgen);
      gbar(p.bcnt, p.bgen);
    }
    out_win(p.A1_0, p.Woutb, p.bout, p.out, Sq - 1, ob, smem, tid);
  }
}

// ================= host =================
extern "C" void kernel_launch(void* const* d_in, const int* in_sizes, int n_in,
                              void* d_out, int out_size, void* d_ws, size_t ws_size,
                              hipStream_t stream) {
  const float* z    = (const float*)d_in[0];
  const float* Wh   = (const float*)d_in[1];
  const float* bh   = (const float*)d_in[2];
  const float* Wc   = (const float*)d_in[3];
  const float* bc   = (const float*)d_in[4];
  const float* Wih0 = (const float*)d_in[5];
  const float* Whh0 = (const float*)d_in[6];
  const float* bih0 = (const float*)d_in[7];
  const float* bhh0 = (const float*)d_in[8];
  const float* Wih1 = (const float*)d_in[9];
  const float* Whh1 = (const float*)d_in[10];
  const float* bih1 = (const float*)d_in[11];
  const float* bhh1 = (const float*)d_in[12];
  const float* Wout = (const float*)d_in[13];
  const float* bout = (const float*)d_in[14];
  float* out = (float*)d_out;

  char* ws = (char*)d_ws;
  size_t off = 0;
  auto carve = [&](size_t bytes) { char* p = ws + off; off = (off + bytes + 255) & ~size_t(255); return p; };
  short* W1r   = (short*)carve((size_t)G4H * K1 * 2);
  short* W2r   = (short*)carve((size_t)G4H * K2q * 2);
  short* Woutb = (short*)carve((size_t)Od * Hd * 2);
  float* b0v   = (float*)carve(G4H * 4);
  float* b1v   = (float*)carve(G4H * 4);
  float* bpro  = (float*)carve(G4H * 4);
  short* A1_0  = (short*)carve((size_t)Bt * K1 * 2);
  short* A1_1  = (short*)carve((size_t)Bt * K1 * 2);
  short* A2_0  = (short*)carve((size_t)Bt * K2q * 2);
  short* A2_1  = (short*)carve((size_t)Bt * K2q * 2);
  float* c1    = (float*)carve((size_t)Bt * Hd * 4);
  float* c2    = (float*)carve((size_t)Bt * Hd * 4);
  unsigned* bar = (unsigned*)carve(256);

  k_conv_w1a<<<16384, 256, 0, stream>>>(Whh0, W1r);
  k_conv_w1b<<<16384, 256, 0, stream>>>(Wih0, Wout, W1r);
  k_conv_w1c<<<2048, 256, 0, stream>>>(Wih0, W1r);
  k_conv_w2 <<<32768, 256, 0, stream>>>(Wih1, Whh1, W2r);
  k_conv_wout<<<256, 256, 0, stream>>>(Wout, Woutb);
  k_vec<<<16, 256, 0, stream>>>(bih0, bhh0, bih1, bhh1, Wih0, bout, b0v, b1v, bpro, bar);
  k_init<<<2048, 256, 0, stream>>>(z, Wh, bh, Wc, bc, A1_0, A2_0, c1, c2);
  k_initz<<<256, 256, 0, stream>>>(z, A1_0, A1_1);

  Params pr{W1r, W2r, Woutb, b0v, b1v, bpro, bout,
            A1_0, A1_1, A2_0, A2_1, c1, c2, out, bar, bar + 1};

  (void)hipFuncSetAttribute((const void*)lstm_main,
                            hipFuncAttributeMaxDynamicSharedMemorySize, 3 * BUFSH * 2);
  lstm_main<<<dim3(NBLK), dim3(256), 3 * BUFSH * 2, stream>>>(pr);
}

// Round 6
// 14078.842 us; speedup vs baseline: 4.3635x; 1.1338x over previous
//
#include <hip/hip_runtime.h>

// Problem dims
#define Lz   128
#define Hd   1024
#define Od   64
#define Sq   256
#define Bt   512
#define K1   1216   // h1(1024) | z(128) | out(64)  -- fold un-materialized (rank-64)
#define K2q  2048   // h1n(1024) | h2(1024)
#define G4H  4096
#define NBLK 272u   // 256 GEMM (8 mb x 32 bn2, 64x128 tiles) + 16 out

typedef __attribute__((ext_vector_type(8))) short  short8;
typedef __attribute__((ext_vector_type(4))) float  floatx4;

__device__ __forceinline__ short f2bf(float x) {
  unsigned u = __float_as_uint(x);
  unsigned r = (u + 0x7fffu + ((u >> 16) & 1u)) >> 16;
  return (short)r;
}
__device__ __forceinline__ float sigf(float x)   { return 1.0f / (1.0f + __expf(-x)); }
__device__ __forceinline__ float tanhf_(float x) { return 1.0f - 2.0f / (__expf(2.0f * x) + 1.0f); }

// cached load (L2-resident; for static data: weights, z)
__device__ __forceinline__ void gl_lds_w(const short* g, void* l) {
  __builtin_amdgcn_global_load_lds(
      (__attribute__((address_space(1))) const void*)g,
      (__attribute__((address_space(3))) void*)l, 16, 0, 0);
}
// coherent dynamic-activation load: sc0|nt|sc1 -> force L2 miss (never stale),
// no L2 allocation (never evicts weights), reads MALL (sees write-through stores)
__device__ __forceinline__ void gl_lds_a(const short* g, void* l) {
  __builtin_amdgcn_global_load_lds(
      (__attribute__((address_space(1))) const void*)g,
      (__attribute__((address_space(3))) void*)l, 16, 0, 19);
}
// write-through coherent h-state store (visible at MALL to all XCDs)
__device__ __forceinline__ void st_wt(short* p, short v) {
  asm volatile("global_store_short %0, %1, off sc0 sc1"
               :: "v"(p), "v"((unsigned)(unsigned short)v) : "memory");
}

#define S_BARRIER() asm volatile("s_barrier" ::: "memory")
#define WAITVM(n)   asm volatile("s_waitcnt vmcnt(" #n ")" ::: "memory")

// ---- fence-free grid barrier: relaxed agent atomics only (visibility proven R4/R5).
__device__ __forceinline__ void gbar(unsigned* cnt, unsigned* gen) {
  __syncthreads();
  if (threadIdx.x == 0) {
    unsigned g = __hip_atomic_load(gen, __ATOMIC_RELAXED, __HIP_MEMORY_SCOPE_AGENT);
    unsigned a = __hip_atomic_fetch_add(cnt, 1u, __ATOMIC_RELAXED, __HIP_MEMORY_SCOPE_AGENT);
    if (a == NBLK - 1u) {
      __hip_atomic_store(cnt, 0u, __ATOMIC_RELAXED, __HIP_MEMORY_SCOPE_AGENT);
      __hip_atomic_store(gen, g + 1u, __ATOMIC_RELAXED, __HIP_MEMORY_SCOPE_AGENT);
    } else {
      while (__hip_atomic_load(gen, __ATOMIC_RELAXED, __HIP_MEMORY_SCOPE_AGENT) == g)
        __builtin_amdgcn_s_sleep(8);
    }
  }
  __syncthreads();
}

// ---- weight row reorder: group bn (0..63) holds 64 rows: gate g (ifgo), j (0..15)
__device__ __forceinline__ int oldrow(int nr) {
  int bn = nr >> 6, rem = nr & 63, g = rem >> 4, jj = rem & 15;
  return g * Hd + bn * 16 + jj;
}

struct Params {
  const short *W1r, *W2r, *Woutb;
  const float *b0v, *b1v, *bout;
  short *A1_0, *A1_1, *A2_0, *A2_1;
  float *c1, *c2, *out;
  unsigned *bcnt, *bgen;
  int *outcnt;
};

// ================= prep kernels =================
__global__ void k_conv_w1a(const float* __restrict__ Whh0, short* __restrict__ W1r) {
  int idx = blockIdx.x * 256 + threadIdx.x;        // 4096*1024
  int nr = idx >> 10, k = idx & 1023;
  W1r[nr * K1 + k] = f2bf(Whh0[oldrow(nr) * Hd + k]);
}
__global__ void k_conv_w1c(const float* __restrict__ Wih0, short* __restrict__ W1r) {
  int idx = blockIdx.x * 256 + threadIdx.x;        // 4096*128 (z cols)
  int nr = idx >> 7, kz = idx & 127;
  W1r[nr * K1 + 1024 + kz] = f2bf(Wih0[oldrow(nr) * (Lz + Od) + kz]);
}
__global__ void k_conv_w1d(const float* __restrict__ Wih0, short* __restrict__ W1r) {
  int idx = blockIdx.x * 256 + threadIdx.x;        // 4096*64 (out-feedback cols)
  int nr = idx >> 6, j = idx & 63;
  W1r[nr * K1 + 1152 + j] = f2bf(Wih0[oldrow(nr) * (Lz + Od) + Lz + j]);
}
__global__ void k_conv_w2(const float* __restrict__ Wih1, const float* __restrict__ Whh1,
                          short* __restrict__ W2r) {
  int idx = blockIdx.x * 256 + threadIdx.x;        // 4096*2048
  int nr = idx >> 11, k = idx & 2047;
  int orow = oldrow(nr);
  float v = (k < Hd) ? Wih1[orow * Hd + k] : Whh1[orow * Hd + (k - Hd)];
  W2r[nr * K2q + k] = f2bf(v);
}
__global__ void k_conv_wout(const float* __restrict__ Wout, short* __restrict__ Woutb) {
  int idx = blockIdx.x * 256 + threadIdx.x;        // 64*1024
  Woutb[idx] = f2bf(Wout[idx]);
}
__global__ void k_vec(const float* __restrict__ bih0, const float* __restrict__ bhh0,
                      const float* __restrict__ bih1, const float* __restrict__ bhh1,
                      float* __restrict__ b0v, float* __restrict__ b1v,
                      int* __restrict__ barzero) {
  int n = blockIdx.x * 256 + threadIdx.x;          // 4096 (original gate order)
  if (n < 64) barzero[n] = 0;                      // zero barrier/counter state
  b0v[n] = bih0[n] + bhh0[n];
  b1v[n] = bih1[n] + bhh1[n];
}
__global__ void k_init(const float* __restrict__ z, const float* __restrict__ Wh,
                       const float* __restrict__ bh, const float* __restrict__ Wc,
                       const float* __restrict__ bc,
                       short* __restrict__ A1_0, short* __restrict__ A2_0,
                       float* __restrict__ c1, float* __restrict__ c2) {
  int idx = blockIdx.x * 256 + threadIdx.x;        // 512*1024
  int m = idx >> 10, n = idx & 1023;
  const float* zr = z + m * Lz;
  const float* whr = Wh + n * Lz;
  const float* wcr = Wc + n * Lz;
  float hh = bh[n], cc = bc[n];
  #pragma unroll 8
  for (int k = 0; k < Lz; ++k) { float zv = zr[k]; hh += zv * whr[k]; cc += zv * wcr[k]; }
  c1[idx] = cc;
  c2[idx] = cc;
  short hb = f2bf(hh);
  A1_0[m * K1 + n] = hb;                 // h1(-1) = h0
  if (n < Od) A1_0[m * K1 + 1152 + n] = 0;   // out(-1) = 0
  A2_0[m * K2q + Hd + n] = hb;           // h2(-1) = h0
}
__global__ void k_initz(const float* __restrict__ z, short* __restrict__ A1_0,
                        short* __restrict__ A1_1) {
  int idx = blockIdx.x * 256 + threadIdx.x;        // 512*128
  int m = idx >> 7, k = idx & 127;
  short v = f2bf(z[idx]);
  A1_0[m * K1 + 1024 + k] = v;
  A1_1[m * K1 + 1024 + k] = v;
}

// ================= main persistent kernel =================
#define MFMA16(a, b, c) __builtin_amdgcn_mfma_f32_16x16x32_bf16(a, b, c, 0, 0, 0)
#define BUFSH 12288   // shorts per LDS buffer: A 64x64 (4096) + W 128x64 (8192)

// 64x128 tile, 4 waves: w = mh*2+gh. XOR-swizzled LDS (R3-proven):
// LDS chunk-slot sl of row r holds global chunk sl^(r&7).
__device__ __forceinline__ void gemm_win(
    const short* __restrict__ Asrc, int astride, int nk, int zstart,
    const short* __restrict__ Wsrc,
    const float* __restrict__ bz, float cr[2][4],
    short* __restrict__ hd0, int hs0, int ho0,
    short* __restrict__ hd1, int hs1, int ho1,
    int m0, int bn2, short* sm, int tid,
    int* __restrict__ ocnt, int othresh)
{
  const int lane = tid & 63, w = tid >> 6;
  const int l15 = lane & 15, q = lane >> 4;
  const int mh = w >> 1, gh = w & 1;
  floatx4 acc[2][4] = {};

  const short* Ab = Asrc + (size_t)m0 * astride;
  const short* Wb = Wsrc + (size_t)(bn2 * 128) * astride;

  auto stage = [&](int kk, int b) {
    const int kb = kk * 64;
    short* as = sm + b * BUFSH;
    short* ws = as + 4096;
    const bool stat = (kk == zstart) || (kk == zstart + 1);   // static z cols: cached
    #pragma unroll
    for (int i = 0; i < 2; ++i) {
      int s = i * 256 + tid;
      int row = s >> 3, cg = (s & 7) ^ (row & 7);
      const short* gp = Ab + (size_t)row * astride + kb + cg * 8;
      if (stat) gl_lds_w(gp, as + s * 8);
      else      gl_lds_a(gp, as + s * 8);
    }
    #pragma unroll
    for (int i = 0; i < 4; ++i) {
      int s = i * 256 + tid;
      int row = s >> 3, cg = (s & 7) ^ (row & 7);
      gl_lds_w(Wb + (size_t)row * astride + kb + cg * 8, ws + s * 8);
    }
  };

  stage(0, 0);
  stage(1, 1);
  for (int kk = 0; kk < nk; ++kk) {
    S_BARRIER();
    if (kk + 2 < nk) {
      if (ocnt && kk + 2 == nk - 1) {     // out-feedback chunk: wait for out-blocks
        while (__hip_atomic_load(ocnt, __ATOMIC_RELAXED, __HIP_MEMORY_SCOPE_AGENT) < othresh)
          __builtin_amdgcn_s_sleep(1);
      }
      stage(kk + 2, (kk + 2) % 3);
      WAITVM(12);
    }
    else if (kk + 1 < nk) { WAITVM(6); }
    else { WAITVM(0); }
    S_BARRIER();
    const short* as = sm + (kk % 3) * BUFSH;
    const short* ws = as + 4096;
    #pragma unroll
    for (int ks = 0; ks < 2; ++ks) {
      const int cc = ks * 4 + q;
      short8 a[2];
      #pragma unroll
      for (int mt = 0; mt < 2; ++mt) {
        const int ra = mh * 32 + mt * 16 + l15;
        a[mt] = *(const short8*)(as + (ra * 8 + (cc ^ (ra & 7))) * 8);
      }
      #pragma unroll
      for (int g = 0; g < 4; ++g) {
        const int rw = gh * 64 + g * 16 + l15;
        short8 b = *(const short8*)(ws + (rw * 8 + (cc ^ (rw & 7))) * 8);
        acc[0][g] = MFMA16(a[0], b, acc[0][g]);
        acc[1][g] = MFMA16(a[1], b, acc[1][g]);
      }
    }
  }
  // fused LSTM cell epilogue; h written through to MALL (cross-XCD coherent)
  #pragma unroll
  for (int mt = 0; mt < 2; ++mt) {
    #pragma unroll
    for (int r = 0; r < 4; ++r) {
      const int mg = m0 + mh * 32 + mt * 16 + q * 4 + r;
      const int colh = bn2 * 32 + gh * 16 + l15;
      float iv = acc[mt][0][r] + bz[0];
      float fv = acc[mt][1][r] + bz[1];
      float gv = acc[mt][2][r] + bz[2];
      float ov = acc[mt][3][r] + bz[3];
      float cn = sigf(fv) * cr[mt][r] + sigf(iv) * tanhf_(gv);
      cr[mt][r] = cn;
      short hb = f2bf(sigf(ov) * tanhf_(cn));
      st_wt(hd0 + (size_t)mg * hs0 + ho0 + colh, hb);
      if (hd1) st_wt(hd1 + (size_t)mg * hs1 + ho1 + colh, hb);
    }
  }
}

// out-blocks: out(tt) = h2(tt)@Wout.T + bout; h2 from A2 h2-slot; publish bf16
// into A1's out-segment + bump completion counter.
__device__ __forceinline__ void out_win(const short* __restrict__ h2src,
    short* __restrict__ a1dst,
    const short* __restrict__ Wo, const float* __restrict__ bout,
    float* __restrict__ out, int tt, int ob, short* sm, int tid,
    int* __restrict__ ocnt)
{
  const int lane = tid & 63, w = tid >> 6;
  const int l15 = lane & 15, q = lane >> 4;
  const int ms = w & 1, nh = w >> 1;
  const int m0 = ob * 32;
  #pragma unroll
  for (int i = 0; i < 16; ++i) {
    int s = i * 256 + tid;
    int row = s >> 7, c = s & 127, cs = c ^ (row & 7);
    gl_lds_a(h2src + (size_t)(m0 + row) * K2q + Hd + cs * 8, sm + s * 8);
  }
  WAITVM(0);
  __syncthreads();
  floatx4 acc[2] = {};
  const short* B0 = Wo + (nh * 32 + l15) * Hd;
  const int ra = ms * 16 + l15;
  for (int kk = 0; kk < Hd; kk += 32) {
    const int ch = (kk >> 3) + q;
    short8 a  = *(const short8*)(sm + (ra * 128 + (ch ^ (ra & 7))) * 8);
    short8 b0 = *(const short8*)(B0 + kk + q * 8);
    short8 b1 = *(const short8*)(B0 + 16 * Hd + kk + q * 8);
    acc[0] = MFMA16(a, b0, acc[0]);
    acc[1] = MFMA16(a, b1, acc[1]);
  }
  #pragma unroll
  for (int s2 = 0; s2 < 2; ++s2)
    #pragma unroll
    for (int r = 0; r < 4; ++r) {
      int m = m0 + ms * 16 + q * 4 + r;
      int n = nh * 32 + s2 * 16 + l15;
      float v = acc[s2][r] + bout[n];
      out[(size_t)m * (Sq * Od) + tt * Od + n] = v;
      if (a1dst) st_wt(a1dst + (size_t)m * K1 + 1152 + n, f2bf(v));
    }
  WAITVM(0);           // drain fp32 + write-through stores before publishing
  __syncthreads();
  if (ocnt && tid == 0)
    __hip_atomic_fetch_add(ocnt, 1, __ATOMIC_RELAXED, __HIP_MEMORY_SCOPE_AGENT);
  __syncthreads();     // protect sm before next step's stage
}

__global__ __launch_bounds__(256, 2) void lstm_main(Params p) {
  extern __shared__ __align__(16) short smem[];   // 3 x 24 KB = 72 KB
  const int tid = threadIdx.x;
  const int blk = blockIdx.x;

  if (blk < 256) {
    const int xcd = blk & 7, j = blk >> 3;
    const int bn2 = xcd * 4 + (j & 3);   // 0..31
    const int m0 = (j >> 2) * 64;        // mb 0..7
    const int lane = tid & 63, w = tid >> 6;
    const int l15 = lane & 15, q = lane >> 4;
    const int mh = w >> 1, gh = w & 1;
    const int colh = bn2 * 32 + gh * 16 + l15;

    float bA[4], bB[4], c1r[2][4], c2r[2][4];
    #pragma unroll
    for (int g = 0; g < 4; ++g) {
      bA[g] = p.b0v[g * Hd + colh];
      bB[g] = p.b1v[g * Hd + colh];
    }
    #pragma unroll
    for (int mt = 0; mt < 2; ++mt)
      #pragma unroll
      for (int r = 0; r < 4; ++r) {
        const int mg = m0 + mh * 32 + mt * 16 + q * 4 + r;
        c1r[mt][r] = p.c1[mg * Hd + colh];
        c2r[mt][r] = p.c2[mg * Hd + colh];
      }

    for (int t = 0; t < Sq; ++t) {
      const int par = t & 1;
      const short* A1p = par ? p.A1_1 : p.A1_0;
      short* A1n = par ? p.A1_0 : p.A1_1;
      short* A2p = par ? p.A2_1 : p.A2_0;
      short* A2n = par ? p.A2_0 : p.A2_1;
      // window A: layer-0 gates; A1 = [h1 | z | out(t-1)], out-chunk flag-guarded
      gemm_win(A1p, K1, 19, 16, p.W1r, bA, c1r,
               A1n, K1, 0, A2p, K2q, 0, m0, bn2, smem, tid,
               p.outcnt, 16 * (t + 1));
      gbar(p.bcnt, p.bgen);
      // window B: layer-1 gates; h2n only into A2n
      gemm_win(A2p, K2q, 32, -2, p.W2r, bB, c2r,
               A2n, K2q, Hd, (short*)nullptr, 0, 0, m0, bn2, smem, tid,
               nullptr, 0);
      gbar(p.bcnt, p.bgen);
    }
  } else {
    const int ob = blk - 256;   // 0..15
    for (int t = 0; t < Sq; ++t) {
      const int par = t & 1;
      const short* A2p = par ? p.A2_1 : p.A2_0;
      short* A1p = par ? p.A1_1 : p.A1_0;
      if (t > 0) {
        out_win(A2p, A1p, p.Woutb, p.bout, p.out, t - 1, ob, smem, tid, p.outcnt);
      } else {
        if (tid == 0)
          __hip_atomic_fetch_add(p.outcnt, 1, __ATOMIC_RELAXED, __HIP_MEMORY_SCOPE_AGENT);
        __syncthreads();
      }
      gbar(p.bcnt, p.bgen);
      gbar(p.bcnt, p.bgen);
    }
    // final: out(255) from h2(255) in A2_0 (phase B of t=255 wrote A2n = A2_0)
    out_win(p.A2_0, (short*)nullptr, p.Woutb, p.bout, p.out, Sq - 1, ob, smem, tid, nullptr);
  }
}

// ================= host =================
extern "C" void kernel_launch(void* const* d_in, const int* in_sizes, int n_in,
                              void* d_out, int out_size, void* d_ws, size_t ws_size,
                              hipStream_t stream) {
  const float* z    = (const float*)d_in[0];
  const float* Wh   = (const float*)d_in[1];
  const float* bh   = (const float*)d_in[2];
  const float* Wc   = (const float*)d_in[3];
  const float* bc   = (const float*)d_in[4];
  const float* Wih0 = (const float*)d_in[5];
  const float* Whh0 = (const float*)d_in[6];
  const float* bih0 = (const float*)d_in[7];
  const float* bhh0 = (const float*)d_in[8];
  const float* Wih1 = (const float*)d_in[9];
  const float* Whh1 = (const float*)d_in[10];
  const float* bih1 = (const float*)d_in[11];
  const float* bhh1 = (const float*)d_in[12];
  const float* Wout = (const float*)d_in[13];
  const float* bout = (const float*)d_in[14];
  float* out = (float*)d_out;

  char* ws = (char*)d_ws;
  size_t off = 0;
  auto carve = [&](size_t bytes) { char* p = ws + off; off = (off + bytes + 255) & ~size_t(255); return p; };
  short* W1r   = (short*)carve((size_t)G4H * K1 * 2);
  short* W2r   = (short*)carve((size_t)G4H * K2q * 2);
  short* Woutb = (short*)carve((size_t)Od * Hd * 2);
  float* b0v   = (float*)carve(G4H * 4);
  float* b1v   = (float*)carve(G4H * 4);
  short* A1_0  = (short*)carve((size_t)Bt * K1 * 2);
  short* A1_1  = (short*)carve((size_t)Bt * K1 * 2);
  short* A2_0  = (short*)carve((size_t)Bt * K2q * 2);
  short* A2_1  = (short*)carve((size_t)Bt * K2q * 2);
  float* c1    = (float*)carve((size_t)Bt * Hd * 4);
  float* c2    = (float*)carve((size_t)Bt * Hd * 4);
  int*   barr  = (int*)carve(256);   // [0]=cnt [1]=gen [2]=outcnt

  k_conv_w1a<<<16384, 256, 0, stream>>>(Whh0, W1r);
  k_conv_w1c<<<2048, 256, 0, stream>>>(Wih0, W1r);
  k_conv_w1d<<<1024, 256, 0, stream>>>(Wih0, W1r);
  k_conv_w2 <<<32768, 256, 0, stream>>>(Wih1, Whh1, W2r);
  k_conv_wout<<<256, 256, 0, stream>>>(Wout, Woutb);
  k_vec<<<16, 256, 0, stream>>>(bih0, bhh0, bih1, bhh1, b0v, b1v, barr);
  k_init<<<2048, 256, 0, stream>>>(z, Wh, bh, Wc, bc, A1_0, A2_0, c1, c2);
  k_initz<<<256, 256, 0, stream>>>(z, A1_0, A1_1);

  Params pr{W1r, W2r, Woutb, b0v, b1v, bout,
            A1_0, A1_1, A2_0, A2_1, c1, c2, out,
            (unsigned*)barr, (unsigned*)(barr + 1), barr + 2};

  (void)hipFuncSetAttribute((const void*)lstm_main,
                            hipFuncAttributeMaxDynamicSharedMemorySize, 3 * BUFSH * 2);
  lstm_main<<<dim3(NBLK), dim3(256), 3 * BUFSH * 2, stream>>>(pr);
}